// Round 8
// baseline (92.956 us; speedup 1.0000x reference)
//
#include <hip/hip_runtime.h>

#define BATCH 8
#define NPTS 9225
#define MQ 4096
#define CAP 64
#define GRID 64
#define NCELLS (GRID * GRID)   // 4096; window = cx±2, cy±2 (5x5 cells)
// coverage margin: >= 2/64 = 0.03125 each side vs r = 0.03 (+fp32-expansion
// slack ~2e-6). ~56 candidates per query.

__device__ __forceinline__ int cell_of(float x, float y) {
  int cx = (int)(x * (float)GRID);
  int cy = (int)(y * (float)GRID);
  cx = min(max(cx, 0), GRID - 1);
  cy = min(max(cy, 0), GRID - 1);
  return cy * GRID + cx;
}

// One block per batch: LDS histogram -> shfl-based scan -> scatter of merged
// 16B records (x, y, idx_bits, 0). (R7 version, unchanged — not the bottleneck.)
__global__ __launch_bounds__(1024) void build_kernel(
    const float* __restrict__ data,
    int* __restrict__ cell_starts,   // [B][NCELLS+1]
    float4* __restrict__ recs) {     // [B][NPTS]
  __shared__ int hist[NCELLS];
  __shared__ int cursor[NCELLS];
  __shared__ int wavesum[16];
  const int b = blockIdx.x;
  const int t = threadIdx.x;
#pragma unroll
  for (int k = 0; k < NCELLS / 1024; ++k) hist[t + k * 1024] = 0;
  __syncthreads();

  const float2* dp = (const float2*)data + (size_t)b * NPTS;
  for (int i = t; i < NPTS; i += 1024)
    atomicAdd(&hist[cell_of(dp[i].x, dp[i].y)], 1);
  __syncthreads();

  const int c0 = hist[4 * t + 0], c1 = hist[4 * t + 1];
  const int c2 = hist[4 * t + 2], c3 = hist[4 * t + 3];
  const int s = c0 + c1 + c2 + c3;
  const int lane = t & 63, wid = t >> 6;
  int v = s;
#pragma unroll
  for (int off = 1; off < 64; off <<= 1) {
    const int u = __shfl_up(v, off, 64);
    if (lane >= off) v += u;
  }
  if (lane == 63) wavesum[wid] = v;
  __syncthreads();
  int woff = 0;
  for (int k = 0; k < wid; ++k) woff += wavesum[k];
  int e = woff + v - s;  // exclusive prefix of cell 4t
  int* cs = cell_starts + b * (NCELLS + 1);
  cs[4 * t + 0] = e; cursor[4 * t + 0] = e; e += c0;
  cs[4 * t + 1] = e; cursor[4 * t + 1] = e; e += c1;
  cs[4 * t + 2] = e; cursor[4 * t + 2] = e; e += c2;
  cs[4 * t + 3] = e; cursor[4 * t + 3] = e; e += c3;
  if (t == 1023) cs[NCELLS] = e;  // == NPTS
  __syncthreads();

  float4* rb = recs + (size_t)b * NPTS;
  for (int i = t; i < NPTS; i += 1024) {
    const float2 p = dp[i];  // re-read (L2 hit)
    const int pos = atomicAdd(&cursor[cell_of(p.x, p.y)], 1);
    rb[pos] = make_float4(p.x, p.y, __int_as_float(i), 0.0f);
  }
}

// One wave per query, 16 waves/block. Preamble fully scalarized via
// readfirstlane (q, cx, cy wave-uniform) -> cell_starts loads and segment
// bookkeeping live in SGPRs / scalar pipe.
__global__ __launch_bounds__(1024) void search_kernel(
    const float* __restrict__ queries, const float* __restrict__ radius_p,
    const int* __restrict__ cell_starts, const float4* __restrict__ recs,
    int* __restrict__ nbr_idx, int* __restrict__ counts) {
#pragma clang fp contract(off)
  __shared__ int hitbuf[16][CAP];
  const int lane = threadIdx.x & 63;
  const int w = __builtin_amdgcn_readfirstlane(threadIdx.x >> 6);
  const int q = blockIdx.x * 16 + w;    // SGPR
  const int b = q >> 12;                // MQ = 4096
  const float r = radius_p[0];
  const float r2 = r * r;
  const float2 qv = ((const float2*)queries)[q];  // uniform address
  const float qx = qv.x, qy = qv.y;
  const float qn = qx * qx + qy * qy;   // mul,mul,add — no fma (matches np)

  const int cx = __builtin_amdgcn_readfirstlane(
      min(max((int)(qx * (float)GRID), 0), GRID - 1));
  const int cy = __builtin_amdgcn_readfirstlane(
      min(max((int)(qy * (float)GRID), 0), GRID - 1));
  const int x0 = max(cx - 2, 0), x1 = min(cx + 2, GRID - 1);
  const int y0 = max(cy - 2, 0), y1 = min(cy + 2, GRID - 1);

  const int csbase = b * (NCELLS + 1);
  int rstart[5], rlen[5];
  int nr = 0;
  for (int y = y0; y <= y1; ++y) {      // scalar loop, 3..5 trips
    const int s0 = cell_starts[csbase + y * GRID + x0];
    const int s1 = cell_starts[csbase + y * GRID + x1 + 1];
    rstart[nr] = s0;
    rlen[nr] = s1 - s0;
    ++nr;
  }
  for (int k = nr; k < 5; ++k) { rstart[k] = 0; rlen[k] = 0; }
  const int L0 = rlen[0];
  const int L1 = L0 + rlen[1];
  const int L2 = L1 + rlen[2];
  const int L3 = L2 + rlen[3];
  const int T = L3 + rlen[4];

  const unsigned long long below = (1ull << lane) - 1ull;
  const float4* rb = recs + (size_t)b * NPTS;
  int h = 0;

  for (int base = 0; base < T; base += 64) {
    const int p = base + lane;
    const bool act = (p < T);
    int i;
    if (p < L0)      i = rstart[0] + p;
    else if (p < L1) i = rstart[1] + (p - L0);
    else if (p < L2) i = rstart[2] + (p - L1);
    else if (p < L3) i = rstart[3] + (p - L2);
    else             i = rstart[4] + (p - L3);
    if (!act) i = 0;  // safe address
    const float4 rec = rb[i];
    const float dx = rec.x, dy = rec.y;
    const int id = __float_as_int(rec.z);
    const float dn = dx * dx + dy * dy;            // mul,mul,add — no fma
    const float cross = qx * dx + qy * dy;         // mul,mul,add — no fma
    const float s = (qn + dn) - 2.0f * cross;      // matches np op order
    const bool in = act && (s <= r2);
    const unsigned long long mask = __ballot(in);
    if (in) {
      const int pos = h + __popcll(mask & below);
      if (pos < CAP) hitbuf[w][pos] = id;
    }
    h += __popcll(mask);
  }

  // gather (same-wave LDS RAW is in-order)
  int v = (lane < h && lane < CAP) ? hitbuf[w][lane] : 0x7fffffff;

  // bitonic sort: k=2..32 sorts each 32-half (high half = all-MAX)
#pragma unroll
  for (int k = 2; k <= 32; k <<= 1) {
#pragma unroll
    for (int j = k >> 1; j >= 1; j >>= 1) {
      const int other = __shfl_xor(v, j, 64);
      const bool keep_min = (((lane & k) == 0) == ((lane & j) == 0));
      v = keep_min ? min(v, other) : max(v, other);
    }
  }
  if (h > 32) {  // final 64-merge only if hits spill past lane 31
#pragma unroll
    for (int j = 32; j >= 1; j >>= 1) {
      const int other = __shfl_xor(v, j, 64);
      const bool keep_min = ((lane & j) == 0);
      v = keep_min ? min(v, other) : max(v, other);
    }
  }

  nbr_idx[(size_t)q * CAP + lane] = (v == 0x7fffffff) ? -1 : v;
  if (lane == 0) counts[q] = h;
}

// Per-batch exclusive scan of 4096 counts -> row_splits[b][0..4096].
// Loads staged through LDS so global reads are coalesced.
__global__ __launch_bounds__(256) void scan_kernel(const int* __restrict__ counts,
                                                   int* __restrict__ row_splits) {
  const int b = blockIdx.x;
  const int t = threadIdx.x;
  const int PER = MQ / 256;  // 16
  __shared__ int buf[MQ + MQ / 16];  // +i/16 pad breaks 16-way bank conflicts
  __shared__ int partial[256];
  const int* c = counts + b * MQ;
#pragma unroll
  for (int k = 0; k < PER; ++k) {
    const int i = t + 256 * k;          // coalesced global read
    buf[i + (i >> 4)] = c[i];
  }
  __syncthreads();
  int local[PER];
  int sum = 0;
#pragma unroll
  for (int k = 0; k < PER; ++k) {
    const int i = t * PER + k;
    local[k] = buf[i + (i >> 4)];
    sum += local[k];
  }
  partial[t] = sum;
  __syncthreads();
  for (int off = 1; off < 256; off <<= 1) {
    int u = (t >= off) ? partial[t - off] : 0;
    __syncthreads();
    partial[t] += u;
    __syncthreads();
  }
  const int excl = (t == 0) ? 0 : partial[t - 1];
  int* rs = row_splits + b * (MQ + 1);
  if (t == 0) rs[0] = 0;
  int run = excl;
#pragma unroll
  for (int k = 0; k < PER; ++k) { run += local[k]; rs[t * PER + k + 1] = run; }
}

extern "C" void kernel_launch(void* const* d_in, const int* in_sizes, int n_in,
                              void* d_out, int out_size, void* d_ws, size_t ws_size,
                              hipStream_t stream) {
  const float* data    = (const float*)d_in[0];
  const float* queries = (const float*)d_in[1];
  const float* radius  = (const float*)d_in[2];
  int* out        = (int*)d_out;
  int* nbr_idx    = out;                       // BATCH*MQ*CAP
  int* row_splits = out + BATCH * MQ * CAP;    // BATCH*(MQ+1)

  // workspace layout (ints); counts+cell_starts = 65544 ints = 262176 B,
  // divisible by 16 -> recs is 16B-aligned.
  int* counts      = (int*)d_ws;                         // 32768
  int* cell_starts = counts + BATCH * MQ;                // 8*4097 = 32776
  float4* recs     = (float4*)(cell_starts + BATCH * (NCELLS + 1));

  hipLaunchKernelGGL(build_kernel, dim3(BATCH), dim3(1024), 0, stream,
                     data, cell_starts, recs);
  hipLaunchKernelGGL(search_kernel, dim3(BATCH * MQ / 16), dim3(1024), 0, stream,
                     queries, radius, cell_starts, recs, nbr_idx, counts);
  hipLaunchKernelGGL(scan_kernel, dim3(BATCH), dim3(256), 0, stream,
                     counts, row_splits);
}